// Round 16
// baseline (120.527 us; speedup 1.0000x reference)
//
#include <hip/hip_runtime.h>
#include <hip/hip_bf16.h>
#include <hip/hip_fp8.h>

// SNN forward, round 16: R14 + NON-TEMPORAL x loads (compile fix of R15).
// Theory: the 179MB x stream evicts the 400KB B slab set from each XCD L2
// (B reuse interval >> L2 turnover), forcing B's ~187MB re-read to L3/HBM
// service rate. Marking x loads 'nt' (no L2 allocation) keeps B L2-resident.
// __builtin_nontemporal_load needs a clang-native vector type -> use
// ext_vector_type(4) float for the A-stage registers.

#define B_    256
#define T_    250
#define NIN   700
#define NHID  512
#define NOUT  20
#define NKT   22          // K-tiles of 32 (704 = 22*32)
#define NSLAB 25          // +3 dummy prefetch slabs

typedef __attribute__((ext_vector_type(4))) float f32x4;

static __device__ __forceinline__ unsigned pack_fp8x4(float f0, float f1,
                                                      float f2, float f3) {
#if __has_builtin(__builtin_amdgcn_cvt_pk_fp8_f32)
  int u = __builtin_amdgcn_cvt_pk_fp8_f32(f0, f1, 0, false);
  u = __builtin_amdgcn_cvt_pk_fp8_f32(f2, f3, u, true);
  return (unsigned)u;
#else
  __hip_fp8_e4m3 q0(f0), q1(f1), q2(f2), q3(f3);
  return (unsigned)q0.__x | ((unsigned)q1.__x << 8) |
         ((unsigned)q2.__x << 16) | ((unsigned)q3.__x << 24);
#endif
}
static __device__ __forceinline__ void gload_lds16(const void* g, void* l) {
  __builtin_amdgcn_global_load_lds(
      (const __attribute__((address_space(1))) unsigned*)g,
      (__attribute__((address_space(3))) unsigned*)l, 16, 0, 0);
}
static __device__ __forceinline__ long u2l(uint2 v) {
  union { uint2 u; long l; } c; c.u = v; return c.l;
}
static __device__ __forceinline__ f32x4 ntld4(const float* p) {
  return __builtin_nontemporal_load((const f32x4*)p);   // global_load ... nt
}
// storage slot s (0..511) -> actual h (within-64: s6=lm*4+j <-> h6=j*16+lm)
static __device__ __forceinline__ int hstoremap(int s) {
  return (s & 0x1C0) | ((s & 3) << 4) | ((s >> 2) & 15);
}

// ---------------- prep: w1 -> fp8 fragment slabs (x16 prescale) ----------------
// slab kt (16KB): [cb 0..31][lane 0..63][8 bytes]
// col = cb*16 + (lane&15); k = kt*32 + (lane>>4)*8 + e
__global__ __launch_bounds__(256) void prep_kernel(
    const float* __restrict__ w1, unsigned char* __restrict__ w1f8) {
  int i = blockIdx.x * 256 + threadIdx.x;
  if (i >= NSLAB * 16384) return;
  int e    = i & 7;
  int lane = (i >> 3) & 63;
  int cb   = (i >> 9) & 31;
  int slab = i >> 14;
  int col = cb * 16 + (lane & 15);
  int k   = slab * 32 + (lane >> 4) * 8 + e;
  unsigned char v = 0;
  if (slab < NKT && k < NIN) {
    __hip_fp8_e4m3 q(16.0f * w1[(size_t)col * NIN + k]);
    v = q.__x;
  }
  w1f8[i] = v;
}

// ---------------- fp8 MFMA GEMM ----------------
// grid = 2*tc; block 1024 thr / 16 waves (2x8), tile 128(m) x 512(h), BK=32.
__global__ __launch_bounds__(1024, 4) void gemm_mfma(
    const float* __restrict__ x, const unsigned char* __restrict__ w1f8,
    const float* __restrict__ alpha, unsigned char* __restrict__ iff,
    int t0, int tc) {
  __shared__ __align__(16) char Al[2][4096];    // fp8 A tile, frag order
  __shared__ __align__(16) char Bl[4][16384];   // fp8 B slabs, quad-buffered

  int tid = threadIdx.x, lane = tid & 63, wave = tid >> 6;
  int wr = wave >> 3, wc = wave & 7;            // 2 x 8 wave grid (64x64)
  int lm = lane & 15, lk = lane >> 4;
  int m0 = blockIdx.x * 128;

  // A stager: thread -> (row srow 0..127, k-quad kq 0..7: 4 f32 each)
  int srow = tid >> 3, kq = tid & 7;
  int m = m0 + srow;
  int bb = m / tc;
  int xrow = bb * T_ + t0 + (m - bb * tc);
  const float* ap = x + (size_t)xrow * NIN;
  int wofs = (srow >> 4) * 512
           + ((((srow & 15) + 16 * (kq >> 1)) * 8) ^ ((kq >> 1) << 4))
           + ((kq & 1) << 2);

  f32x4 acc[4][4];
#pragma unroll
  for (int i = 0; i < 4; ++i)
#pragma unroll
    for (int j = 0; j < 4; ++j) acc[i][j] = (f32x4){0.f, 0.f, 0.f, 0.f};

  f32x4 sA, sB, sC;   // 3 named A-stage sets; set s holds A(k), k===s (mod 3)

#define LOADA(D, KT) do { int k0_ = (KT) * 32 + kq * 4;                      \
    int a0_ = (k0_ + 4 <= NIN) ? k0_ : 0;                                    \
    D = ntld4(ap + a0_); } while (0)
    // nt: x is stream-once; don't evict B from L2. garbage at padded k is
    // fine: B is zero there -> product 0

#define WRITEA(BUF, S) do {                                                  \
    *(unsigned*)(&Al[BUF][wofs]) = pack_fp8x4(S.x, S.y, S.z, S.w);           \
  } while (0)

#define STAGEB(KT) do {                                                      \
    const char* gs_ = (const char*)w1f8 + ((size_t)(KT) << 14)               \
                    + wave * 1024 + lane * 16;                               \
    gload_lds16(gs_, Bl[(KT) & 3] + wave * 1024); } while (0)

  // prologue: B0+A0 -> drain -> Al[0]; issue {B1,A1,B2,A2} (stay outstanding)
  STAGEB(0);
  LOADA(sA, 0);
  asm volatile("s_waitcnt vmcnt(0)" ::: "memory");
  __builtin_amdgcn_sched_barrier(0);
  WRITEA(0, sA);
  STAGEB(1);
  LOADA(sB, 1);
  STAGEB(2);
  LOADA(sC, 2);
  asm volatile("s_waitcnt lgkmcnt(0)" ::: "memory");
  __builtin_amdgcn_s_barrier();
  __builtin_amdgcn_sched_barrier(0);

  // iter kt: LDS has A(kt),B(kt); outstanding FIFO = {B,A}(kt+1), {B,A}(kt+2).
  // Issue {B,A}(kt+3) -> 6 out; vmcnt(4) drains kt+1 (issued 2 iters ago).
#pragma unroll
  for (int kt = 0; kt < NKT; ++kt) {
    STAGEB(kt + 3);                           // dummy zero slabs at 22,23,24
    {
      int kc = (kt + 3 < NKT) ? kt + 3 : 0;   // clamped dummy keeps vm count
      if ((kt % 3) == 0)      { LOADA(sA, kc); }
      else if ((kt % 3) == 1) { LOADA(sB, kc); }
      else                    { LOADA(sC, kc); }
    }
    asm volatile("s_waitcnt vmcnt(4)" ::: "memory");
    __builtin_amdgcn_sched_barrier(0);
    // write A(kt+1) (its load drained above; held in set (kt+1)%3)
    if (((kt + 1) % 3) == 0)      { WRITEA((kt + 1) & 1, sA); }
    else if (((kt + 1) % 3) == 1) { WRITEA((kt + 1) & 1, sB); }
    else                          { WRITEA((kt + 1) & 1, sC); }
    // fragments + 16 MFMA
    {
      const char* Ab = Al[kt & 1];
      const char* Bb = Bl[kt & 3];
      int aswz = (lane * 8) ^ (lk << 4);
      long af[4], bf[4];
#pragma unroll
      for (int i = 0; i < 4; ++i)
        af[i] = u2l(*(const uint2*)(&Ab[(wr * 4 + i) * 512 + aswz]));
#pragma unroll
      for (int j = 0; j < 4; ++j)
        bf[j] = u2l(*(const uint2*)(&Bb[(wc * 4 + j) * 512 + lane * 8]));
#pragma unroll
      for (int i = 0; i < 4; ++i)
#pragma unroll
        for (int j = 0; j < 4; ++j)
          acc[i][j] = __builtin_amdgcn_mfma_f32_16x16x32_fp8_fp8(
              af[i], bf[j], acc[i][j], 0, 0, 0);
    }
    asm volatile("s_waitcnt lgkmcnt(0)" ::: "memory");
    __builtin_amdgcn_s_barrier();
    __builtin_amdgcn_sched_barrier(0);
  }
  // drain trailing dummy gloads before LDS dealloc / epilogue
  asm volatile("s_waitcnt vmcnt(0) lgkmcnt(0)" ::: "memory");
#undef LOADA
#undef WRITEA
#undef STAGEB

  // epilogue: scale by (1-alpha)/16, pack 4 fp8 -> u32 at permuted slot
  float scl[4];
#pragma unroll
  for (int j = 0; j < 4; ++j)
    scl[j] = (1.0f - alpha[wc * 64 + j * 16 + lm]) * 0.0625f;
#pragma unroll
  for (int i = 0; i < 4; ++i) {
#pragma unroll
    for (int r = 0; r < 4; ++r) {
      int row = m0 + wr * 64 + i * 16 + lk * 4 + r;
      unsigned u = pack_fp8x4(acc[i][0][r] * scl[0], acc[i][1][r] * scl[1],
                              acc[i][2][r] * scl[2], acc[i][3][r] * scl[3]);
      *(unsigned*)(iff + (size_t)row * NHID + wc * 64 + lm * 4) = u;
    }
  }
}

// ---------------- fused recurrence (unchanged from R14) ----------------
__global__ __launch_bounds__(64) void snn_recur(
    const unsigned char* __restrict__ iff, const float* __restrict__ wrec,
    const float* __restrict__ wout,
    const float* __restrict__ alpha, const float* __restrict__ rho,
    const float* __restrict__ beta_a, const float* __restrict__ beta_out,
    float* __restrict__ state, int* __restrict__ flags,
    float* __restrict__ dout, int Tc, int first, int last) {
  int lane = threadIdx.x;
  int b = blockIdx.x;
  int hbase = lane * 8;
  const unsigned char* ib = iff + (size_t)b * Tc * NHID + hbase;

  float* v1s = state;
  float* a1s = state + B_ * NHID;
  float* sps = state + 2 * B_ * NHID;
  float* vos = state + 3 * B_ * NHID;
  float* oss = vos + B_ * NOUT;

  int hact[8];
#pragma unroll
  for (int r = 0; r < 8; ++r) hact[r] = hstoremap(hbase + r);

  float v1[8], a1[8], sp[8], al[8], rh[8], ba[8];
#pragma unroll
  for (int r = 0; r < 8; ++r) {
    int h = hact[r];
    al[r] = alpha[h]; rh[r] = rho[h]; ba[r] = beta_a[h];
    if (first) { v1[r] = 0.f; a1[r] = 0.f; sp[r] = 0.f; }
    else {
      v1[r] = v1s[(size_t)b * NHID + hbase + r];
      a1[r] = a1s[(size_t)b * NHID + hbase + r];
      sp[r] = sps[(size_t)b * NHID + hbase + r];
    }
  }
  float vout = 0.f, osum = 0.f, bo = 0.f;
  if (lane < NOUT) {
    bo = beta_out[lane];
    if (!first) { vout = vos[b * NOUT + lane]; osum = oss[b * NOUT + lane]; }
  }

  int mode = first ? 0 : flags[b];
  int tle = 0;

  if (mode == 0) {
    uint2 pf[8];
#pragma unroll
    for (int j = 0; j < 8; ++j) {
      int tl = (j < Tc) ? j : (Tc - 1);
      pf[j] = *(const uint2*)(ib + (size_t)tl * NHID);
    }
    bool esc = false;
    for (int tb = 0; tb < Tc && !esc; tb += 8) {
#pragma unroll
      for (int j = 0; j < 8; ++j) {
        int tl = tb + j;
        if (!esc && tl < Tc) {
          float tv[8];
#pragma unroll
          for (int r = 0; r < 8; ++r) {
            unsigned w = (r < 4) ? pf[j].x : pf[j].y;
            __hip_fp8_e4m3 q; q.__x = (unsigned char)((w >> ((r & 3) * 8)) & 255u);
            tv[r] = al[r] * v1[r] + (float)q;   // iff pre-scaled by (1-alpha)
          }
          float m01 = fmaxf(tv[0], tv[1]), m23 = fmaxf(tv[2], tv[3]);
          float m45 = fmaxf(tv[4], tv[5]), m67 = fmaxf(tv[6], tv[7]);
          float mx = fmaxf(fmaxf(m01, m23), fmaxf(m45, m67));
          if (__ballot(mx > 1.0f)) {
            esc = true; tle = tl;
          } else {
#pragma unroll
            for (int r = 0; r < 8; ++r) v1[r] = tv[r];
            int nt = (tl + 8 < Tc) ? (tl + 8) : (Tc - 1);
            pf[j] = *(const uint2*)(ib + (size_t)nt * NHID);
          }
        }
      }
    }
    if (!esc) tle = Tc;
    mode = esc ? 1 : 0;
  }

  unsigned long long mask[8];
#pragma unroll
  for (int r = 0; r < 8; ++r) mask[r] = __ballot(sp[r] != 0.f);

  for (int tl = tle; tl < Tc; ++tl) {
    uint2 w2 = *(const uint2*)(ib + (size_t)tl * NHID);
    float iv[8];
#pragma unroll
    for (int r = 0; r < 8; ++r) {
      unsigned w = (r < 4) ? w2.x : w2.y;
      __hip_fp8_e4m3 q; q.__x = (unsigned char)((w >> ((r & 3) * 8)) & 255u);
      iv[r] = (float)q;
    }
    unsigned long long anyp = mask[0] | mask[1] | mask[2] | mask[3] |
                              mask[4] | mask[5] | mask[6] | mask[7];
    if (anyp) {
      float rec[8] = {0.f,0.f,0.f,0.f,0.f,0.f,0.f,0.f};
#pragma unroll
      for (int r2 = 0; r2 < 8; ++r2) {
        unsigned long long mm = mask[r2];
        while (mm) {
          int l2 = __ffsll(mm) - 1; mm &= (mm - 1);
          int hp = hstoremap(l2 * 8 + r2);
#pragma unroll
          for (int r = 0; r < 8; ++r)
            rec[r] += wrec[(size_t)hact[r] * NHID + hp];
        }
      }
#pragma unroll
      for (int r = 0; r < 8; ++r) iv[r] += (1.0f - al[r]) * rec[r];
    }

    float s[8];
#pragma unroll
    for (int r = 0; r < 8; ++r) {
      a1[r] = rh[r] * a1[r] + ba[r] * sp[r];
      v1[r] = al[r] * v1[r] + iv[r] - a1[r];
      s[r] = (v1[r] - 1.0f > 0.0f) ? 1.0f : 0.0f;
      v1[r] -= s[r];
      sp[r] = s[r];
      mask[r] = __ballot(s[r] != 0.f);
    }

    unsigned long long anyc = mask[0] | mask[1] | mask[2] | mask[3] |
                              mask[4] | mask[5] | mask[6] | mask[7];
    if (lane < NOUT) {
      float io = 0.f;
      if (anyc) {
#pragma unroll
        for (int r2 = 0; r2 < 8; ++r2) {
          unsigned long long mm = mask[r2];
          while (mm) {
            int l2 = __ffsll(mm) - 1; mm &= (mm - 1);
            int hp = hstoremap(l2 * 8 + r2);
            io += wout[(size_t)lane * NHID + hp];
          }
        }
      }
      vout = bo * vout + (1.0f - bo) * io;
      float so = (vout - 1.0f > 0.0f) ? 1.0f : 0.0f;
      vout -= so;
      osum += vout;
    }
  }

  if (last) {
    if (lane < NOUT) dout[b * NOUT + lane] = osum / (float)T_;
  } else {
#pragma unroll
    for (int r = 0; r < 8; ++r) {
      v1s[(size_t)b * NHID + hbase + r] = v1[r];
      a1s[(size_t)b * NHID + hbase + r] = a1[r];
      sps[(size_t)b * NHID + hbase + r] = sp[r];
    }
    if (lane < NOUT) { vos[b * NOUT + lane] = vout; oss[b * NOUT + lane] = osum; }
    if (lane == 0) flags[b] = mode;
  }
}

extern "C" void kernel_launch(void* const* d_in, const int* in_sizes, int n_in,
                              void* d_out, int out_size, void* d_ws, size_t ws_size,
                              hipStream_t stream) {
  const float* x      = (const float*)d_in[0];
  const float* w1     = (const float*)d_in[1];
  const float* wrec   = (const float*)d_in[2];
  const float* wout   = (const float*)d_in[3];
  const float* alpha  = (const float*)d_in[4];
  const float* rho    = (const float*)d_in[5];
  const float* beta_a = (const float*)d_in[6];
  const float* bout   = (const float*)d_in[7];
  float* out = (float*)d_out;

  char* ws = (char*)d_ws;
  const size_t w1f8_bytes = (size_t)NSLAB * 16384;                           // 400 KB
  const size_t state_off = w1f8_bytes;
  const size_t state_bytes = (size_t)(3 * B_ * NHID + 2 * B_ * NOUT) * 4;
  const size_t flags_off = state_off + state_bytes;
  const size_t iff_off   = flags_off + B_ * 4;

  unsigned char* w1f8 = (unsigned char*)(ws);
  float*  statep = (float*)(ws + state_off);
  int*    flagsp = (int*)(ws + flags_off);
  unsigned char* iff = (unsigned char*)(ws + iff_off);

  const size_t per_step = (size_t)B_ * NHID;  // 128 KB per timestep (fp8)
  long long avail = (long long)ws_size - (long long)iff_off;
  int Tc = (int)(avail / (long long)per_step);
  if (Tc > T_) Tc = T_;
  if (Tc < 1) Tc = 1;

  prep_kernel<<<dim3((NSLAB * 16384 + 255) / 256), dim3(256), 0, stream>>>(
      w1, w1f8);

  for (int t0 = 0; t0 < T_; t0 += Tc) {
    int tc = (T_ - t0 < Tc) ? (T_ - t0) : Tc;
    gemm_mfma<<<dim3(2 * tc), dim3(1024), 0, stream>>>(
        x, w1f8, alpha, iff, t0, tc);
    snn_recur<<<dim3(B_), dim3(64), 0, stream>>>(
        iff, wrec, wout, alpha, rho, beta_a, bout, statep, flagsp, out,
        tc, (t0 == 0) ? 1 : 0, (t0 + tc >= T_) ? 1 : 0);
  }
}

// Round 17
// 89.883 us; speedup vs baseline: 1.3409x; 1.3409x over previous
//
#include <hip/hip_runtime.h>
#include <hip/hip_bf16.h>
#include <hip/hip_fp8.h>

// SNN forward, round 17: R14 (best, 91.1us) minus pipeline waste.
// - exact compile-time pipeline tail: no dummy B slabs, no clamped dummy A
//   loads (saves ~48MB of junk port traffic); vmcnt 4 -> 2 -> 0 over the
//   last three iterations; last iteration has no trailing barrier.
// - NT-load experiment reverted (R16: regressed, x lost L3 residency).

#define B_    256
#define T_    250
#define NIN   700
#define NHID  512
#define NOUT  20
#define NKT   22          // K-tiles of 32 (704 = 22*32)

typedef __attribute__((ext_vector_type(4))) float f32x4;

static __device__ __forceinline__ unsigned pack_fp8x4(float f0, float f1,
                                                      float f2, float f3) {
#if __has_builtin(__builtin_amdgcn_cvt_pk_fp8_f32)
  int u = __builtin_amdgcn_cvt_pk_fp8_f32(f0, f1, 0, false);
  u = __builtin_amdgcn_cvt_pk_fp8_f32(f2, f3, u, true);
  return (unsigned)u;
#else
  __hip_fp8_e4m3 q0(f0), q1(f1), q2(f2), q3(f3);
  return (unsigned)q0.__x | ((unsigned)q1.__x << 8) |
         ((unsigned)q2.__x << 16) | ((unsigned)q3.__x << 24);
#endif
}
static __device__ __forceinline__ void gload_lds16(const void* g, void* l) {
  __builtin_amdgcn_global_load_lds(
      (const __attribute__((address_space(1))) unsigned*)g,
      (__attribute__((address_space(3))) unsigned*)l, 16, 0, 0);
}
static __device__ __forceinline__ long u2l(uint2 v) {
  union { uint2 u; long l; } c; c.u = v; return c.l;
}
// storage slot s (0..511) -> actual h (within-64: s6=lm*4+j <-> h6=j*16+lm)
static __device__ __forceinline__ int hstoremap(int s) {
  return (s & 0x1C0) | ((s & 3) << 4) | ((s >> 2) & 15);
}

// ---------------- prep: w1 -> fp8 fragment slabs (x16 prescale) ----------------
// slab kt (16KB): [cb 0..31][lane 0..63][8 bytes]
// col = cb*16 + (lane&15); k = kt*32 + (lane>>4)*8 + e
__global__ __launch_bounds__(256) void prep_kernel(
    const float* __restrict__ w1, unsigned char* __restrict__ w1f8) {
  int i = blockIdx.x * 256 + threadIdx.x;
  if (i >= NKT * 16384) return;
  int e    = i & 7;
  int lane = (i >> 3) & 63;
  int cb   = (i >> 9) & 31;
  int slab = i >> 14;
  int col = cb * 16 + (lane & 15);
  int k   = slab * 32 + (lane >> 4) * 8 + e;
  unsigned char v = 0;
  if (k < NIN) {
    __hip_fp8_e4m3 q(16.0f * w1[(size_t)col * NIN + k]);
    v = q.__x;
  }
  w1f8[i] = v;
}

// ---------------- fp8 MFMA GEMM ----------------
// grid = 2*tc; block 1024 thr / 16 waves (2x8), tile 128(m) x 512(h), BK=32.
__global__ __launch_bounds__(1024, 4) void gemm_mfma(
    const float* __restrict__ x, const unsigned char* __restrict__ w1f8,
    const float* __restrict__ alpha, unsigned char* __restrict__ iff,
    int t0, int tc) {
  __shared__ __align__(16) char Al[2][4096];    // fp8 A tile, frag order
  __shared__ __align__(16) char Bl[4][16384];   // fp8 B slabs, quad-buffered

  int tid = threadIdx.x, lane = tid & 63, wave = tid >> 6;
  int wr = wave >> 3, wc = wave & 7;            // 2 x 8 wave grid (64x64)
  int lm = lane & 15, lk = lane >> 4;
  int m0 = blockIdx.x * 128;

  // A stager: thread -> (row srow 0..127, k-quad kq 0..7: 4 f32 each)
  int srow = tid >> 3, kq = tid & 7;
  int m = m0 + srow;
  int bb = m / tc;
  int xrow = bb * T_ + t0 + (m - bb * tc);
  const float* ap = x + (size_t)xrow * NIN;
  int wofs = (srow >> 4) * 512
           + ((((srow & 15) + 16 * (kq >> 1)) * 8) ^ ((kq >> 1) << 4))
           + ((kq & 1) << 2);

  f32x4 acc[4][4];
#pragma unroll
  for (int i = 0; i < 4; ++i)
#pragma unroll
    for (int j = 0; j < 4; ++j) acc[i][j] = (f32x4){0.f, 0.f, 0.f, 0.f};

  float4 sA, sB, sC;   // 3 named A-stage sets; set s holds A(k), k===s (mod 3)

#define LOADA(D, KT) do { int k0_ = (KT) * 32 + kq * 4;                      \
    int a0_ = (k0_ + 4 <= NIN) ? k0_ : 0;                                    \
    D = *(const float4*)(ap + a0_); } while (0)
    // garbage at padded k is fine: B is zero there -> product 0

#define WRITEA(BUF, S) do {                                                  \
    *(unsigned*)(&Al[BUF][wofs]) = pack_fp8x4(S.x, S.y, S.z, S.w);           \
  } while (0)

#define STAGEB(KT) do {                                                      \
    const char* gs_ = (const char*)w1f8 + ((size_t)(KT) << 14)               \
                    + wave * 1024 + lane * 16;                               \
    gload_lds16(gs_, Bl[(KT) & 3] + wave * 1024); } while (0)

  // prologue: B0+A0 -> drain -> Al[0]; issue {B1,A1,B2,A2} (stay outstanding)
  STAGEB(0);
  LOADA(sA, 0);
  asm volatile("s_waitcnt vmcnt(0)" ::: "memory");
  __builtin_amdgcn_sched_barrier(0);
  WRITEA(0, sA);
  STAGEB(1);
  LOADA(sB, 1);
  STAGEB(2);
  LOADA(sC, 2);
  asm volatile("s_waitcnt lgkmcnt(0)" ::: "memory");
  __builtin_amdgcn_s_barrier();
  __builtin_amdgcn_sched_barrier(0);

  // Invariant entering iter kt: LDS has A(kt),B(kt); outstanding vm FIFO =
  // {B,A}(kt+1), {B,A}(kt+2)  (4 ops; empty tail as kt+1/kt+2 pass NKT-1).
  // kt<=NKT-4: issue {B,A}(kt+3) -> vmcnt(4) drains kt+1.
  // kt==NKT-3: no issue -> vmcnt(2). kt==NKT-2: vmcnt(0). kt==NKT-1: compute.
#pragma unroll
  for (int kt = 0; kt < NKT; ++kt) {
    if (kt + 3 < NKT) {
      STAGEB(kt + 3);
      if ((kt % 3) == 0)      { LOADA(sA, kt + 3); }
      else if ((kt % 3) == 1) { LOADA(sB, kt + 3); }
      else                    { LOADA(sC, kt + 3); }
      asm volatile("s_waitcnt vmcnt(4)" ::: "memory");
    } else if (kt + 3 == NKT) {         // kt = NKT-3
      asm volatile("s_waitcnt vmcnt(2)" ::: "memory");
    } else if (kt + 2 == NKT) {         // kt = NKT-2
      asm volatile("s_waitcnt vmcnt(0)" ::: "memory");
    }
    __builtin_amdgcn_sched_barrier(0);
    if (kt + 1 < NKT) {   // write A(kt+1) (drained above; set (kt+1)%3)
      if (((kt + 1) % 3) == 0)      { WRITEA((kt + 1) & 1, sA); }
      else if (((kt + 1) % 3) == 1) { WRITEA((kt + 1) & 1, sB); }
      else                          { WRITEA((kt + 1) & 1, sC); }
    }
    // fragments + 16 MFMA
    {
      const char* Ab = Al[kt & 1];
      const char* Bb = Bl[kt & 3];
      int aswz = (lane * 8) ^ (lk << 4);
      long af[4], bf[4];
#pragma unroll
      for (int i = 0; i < 4; ++i)
        af[i] = u2l(*(const uint2*)(&Ab[(wr * 4 + i) * 512 + aswz]));
#pragma unroll
      for (int j = 0; j < 4; ++j)
        bf[j] = u2l(*(const uint2*)(&Bb[(wc * 4 + j) * 512 + lane * 8]));
#pragma unroll
      for (int i = 0; i < 4; ++i)
#pragma unroll
        for (int j = 0; j < 4; ++j)
          acc[i][j] = __builtin_amdgcn_mfma_f32_16x16x32_fp8_fp8(
              af[i], bf[j], acc[i][j], 0, 0, 0);
    }
    if (kt + 1 < NKT) {
      asm volatile("s_waitcnt lgkmcnt(0)" ::: "memory");
      __builtin_amdgcn_s_barrier();
      __builtin_amdgcn_sched_barrier(0);
    }
  }
#undef LOADA
#undef WRITEA
#undef STAGEB

  // epilogue: scale by (1-alpha)/16, pack 4 fp8 -> u32 at permuted slot
  float scl[4];
#pragma unroll
  for (int j = 0; j < 4; ++j)
    scl[j] = (1.0f - alpha[wc * 64 + j * 16 + lm]) * 0.0625f;
#pragma unroll
  for (int i = 0; i < 4; ++i) {
#pragma unroll
    for (int r = 0; r < 4; ++r) {
      int row = m0 + wr * 64 + i * 16 + lk * 4 + r;
      unsigned u = pack_fp8x4(acc[i][0][r] * scl[0], acc[i][1][r] * scl[1],
                              acc[i][2][r] * scl[2], acc[i][3][r] * scl[3]);
      *(unsigned*)(iff + (size_t)row * NHID + wc * 64 + lm * 4) = u;
    }
  }
}

// ---------------- fused recurrence (unchanged from R14) ----------------
__global__ __launch_bounds__(64) void snn_recur(
    const unsigned char* __restrict__ iff, const float* __restrict__ wrec,
    const float* __restrict__ wout,
    const float* __restrict__ alpha, const float* __restrict__ rho,
    const float* __restrict__ beta_a, const float* __restrict__ beta_out,
    float* __restrict__ state, int* __restrict__ flags,
    float* __restrict__ dout, int Tc, int first, int last) {
  int lane = threadIdx.x;
  int b = blockIdx.x;
  int hbase = lane * 8;
  const unsigned char* ib = iff + (size_t)b * Tc * NHID + hbase;

  float* v1s = state;
  float* a1s = state + B_ * NHID;
  float* sps = state + 2 * B_ * NHID;
  float* vos = state + 3 * B_ * NHID;
  float* oss = vos + B_ * NOUT;

  int hact[8];
#pragma unroll
  for (int r = 0; r < 8; ++r) hact[r] = hstoremap(hbase + r);

  float v1[8], a1[8], sp[8], al[8], rh[8], ba[8];
#pragma unroll
  for (int r = 0; r < 8; ++r) {
    int h = hact[r];
    al[r] = alpha[h]; rh[r] = rho[h]; ba[r] = beta_a[h];
    if (first) { v1[r] = 0.f; a1[r] = 0.f; sp[r] = 0.f; }
    else {
      v1[r] = v1s[(size_t)b * NHID + hbase + r];
      a1[r] = a1s[(size_t)b * NHID + hbase + r];
      sp[r] = sps[(size_t)b * NHID + hbase + r];
    }
  }
  float vout = 0.f, osum = 0.f, bo = 0.f;
  if (lane < NOUT) {
    bo = beta_out[lane];
    if (!first) { vout = vos[b * NOUT + lane]; osum = oss[b * NOUT + lane]; }
  }

  int mode = first ? 0 : flags[b];
  int tle = 0;

  if (mode == 0) {
    uint2 pf[8];
#pragma unroll
    for (int j = 0; j < 8; ++j) {
      int tl = (j < Tc) ? j : (Tc - 1);
      pf[j] = *(const uint2*)(ib + (size_t)tl * NHID);
    }
    bool esc = false;
    for (int tb = 0; tb < Tc && !esc; tb += 8) {
#pragma unroll
      for (int j = 0; j < 8; ++j) {
        int tl = tb + j;
        if (!esc && tl < Tc) {
          float tv[8];
#pragma unroll
          for (int r = 0; r < 8; ++r) {
            unsigned w = (r < 4) ? pf[j].x : pf[j].y;
            __hip_fp8_e4m3 q; q.__x = (unsigned char)((w >> ((r & 3) * 8)) & 255u);
            tv[r] = al[r] * v1[r] + (float)q;   // iff pre-scaled by (1-alpha)
          }
          float m01 = fmaxf(tv[0], tv[1]), m23 = fmaxf(tv[2], tv[3]);
          float m45 = fmaxf(tv[4], tv[5]), m67 = fmaxf(tv[6], tv[7]);
          float mx = fmaxf(fmaxf(m01, m23), fmaxf(m45, m67));
          if (__ballot(mx > 1.0f)) {
            esc = true; tle = tl;
          } else {
#pragma unroll
            for (int r = 0; r < 8; ++r) v1[r] = tv[r];
            int nt = (tl + 8 < Tc) ? (tl + 8) : (Tc - 1);
            pf[j] = *(const uint2*)(ib + (size_t)nt * NHID);
          }
        }
      }
    }
    if (!esc) tle = Tc;
    mode = esc ? 1 : 0;
  }

  unsigned long long mask[8];
#pragma unroll
  for (int r = 0; r < 8; ++r) mask[r] = __ballot(sp[r] != 0.f);

  for (int tl = tle; tl < Tc; ++tl) {
    uint2 w2 = *(const uint2*)(ib + (size_t)tl * NHID);
    float iv[8];
#pragma unroll
    for (int r = 0; r < 8; ++r) {
      unsigned w = (r < 4) ? w2.x : w2.y;
      __hip_fp8_e4m3 q; q.__x = (unsigned char)((w >> ((r & 3) * 8)) & 255u);
      iv[r] = (float)q;
    }
    unsigned long long anyp = mask[0] | mask[1] | mask[2] | mask[3] |
                              mask[4] | mask[5] | mask[6] | mask[7];
    if (anyp) {
      float rec[8] = {0.f,0.f,0.f,0.f,0.f,0.f,0.f,0.f};
#pragma unroll
      for (int r2 = 0; r2 < 8; ++r2) {
        unsigned long long mm = mask[r2];
        while (mm) {
          int l2 = __ffsll(mm) - 1; mm &= (mm - 1);
          int hp = hstoremap(l2 * 8 + r2);
#pragma unroll
          for (int r = 0; r < 8; ++r)
            rec[r] += wrec[(size_t)hact[r] * NHID + hp];
        }
      }
#pragma unroll
      for (int r = 0; r < 8; ++r) iv[r] += (1.0f - al[r]) * rec[r];
    }

    float s[8];
#pragma unroll
    for (int r = 0; r < 8; ++r) {
      a1[r] = rh[r] * a1[r] + ba[r] * sp[r];
      v1[r] = al[r] * v1[r] + iv[r] - a1[r];
      s[r] = (v1[r] - 1.0f > 0.0f) ? 1.0f : 0.0f;
      v1[r] -= s[r];
      sp[r] = s[r];
      mask[r] = __ballot(s[r] != 0.f);
    }

    unsigned long long anyc = mask[0] | mask[1] | mask[2] | mask[3] |
                              mask[4] | mask[5] | mask[6] | mask[7];
    if (lane < NOUT) {
      float io = 0.f;
      if (anyc) {
#pragma unroll
        for (int r2 = 0; r2 < 8; ++r2) {
          unsigned long long mm = mask[r2];
          while (mm) {
            int l2 = __ffsll(mm) - 1; mm &= (mm - 1);
            int hp = hstoremap(l2 * 8 + r2);
            io += wout[(size_t)lane * NHID + hp];
          }
        }
      }
      vout = bo * vout + (1.0f - bo) * io;
      float so = (vout - 1.0f > 0.0f) ? 1.0f : 0.0f;
      vout -= so;
      osum += vout;
    }
  }

  if (last) {
    if (lane < NOUT) dout[b * NOUT + lane] = osum / (float)T_;
  } else {
#pragma unroll
    for (int r = 0; r < 8; ++r) {
      v1s[(size_t)b * NHID + hbase + r] = v1[r];
      a1s[(size_t)b * NHID + hbase + r] = a1[r];
      sps[(size_t)b * NHID + hbase + r] = sp[r];
    }
    if (lane < NOUT) { vos[b * NOUT + lane] = vout; oss[b * NOUT + lane] = osum; }
    if (lane == 0) flags[b] = mode;
  }
}

extern "C" void kernel_launch(void* const* d_in, const int* in_sizes, int n_in,
                              void* d_out, int out_size, void* d_ws, size_t ws_size,
                              hipStream_t stream) {
  const float* x      = (const float*)d_in[0];
  const float* w1     = (const float*)d_in[1];
  const float* wrec   = (const float*)d_in[2];
  const float* wout   = (const float*)d_in[3];
  const float* alpha  = (const float*)d_in[4];
  const float* rho    = (const float*)d_in[5];
  const float* beta_a = (const float*)d_in[6];
  const float* bout   = (const float*)d_in[7];
  float* out = (float*)d_out;

  char* ws = (char*)d_ws;
  const size_t w1f8_bytes = (size_t)NKT * 16384;                             // 352 KB
  const size_t state_off = w1f8_bytes;
  const size_t state_bytes = (size_t)(3 * B_ * NHID + 2 * B_ * NOUT) * 4;
  const size_t flags_off = state_off + state_bytes;
  const size_t iff_off   = flags_off + B_ * 4;

  unsigned char* w1f8 = (unsigned char*)(ws);
  float*  statep = (float*)(ws + state_off);
  int*    flagsp = (int*)(ws + flags_off);
  unsigned char* iff = (unsigned char*)(ws + iff_off);

  const size_t per_step = (size_t)B_ * NHID;  // 128 KB per timestep (fp8)
  long long avail = (long long)ws_size - (long long)iff_off;
  int Tc = (int)(avail / (long long)per_step);
  if (Tc > T_) Tc = T_;
  if (Tc < 1) Tc = 1;

  prep_kernel<<<dim3((NKT * 16384 + 255) / 256), dim3(256), 0, stream>>>(
      w1, w1f8);

  for (int t0 = 0; t0 < T_; t0 += Tc) {
    int tc = (T_ - t0 < Tc) ? (T_ - t0) : Tc;
    gemm_mfma<<<dim3(2 * tc), dim3(1024), 0, stream>>>(
        x, w1f8, alpha, iff, t0, tc);
    snn_recur<<<dim3(B_), dim3(64), 0, stream>>>(
        iff, wrec, wout, alpha, rho, beta_a, bout, statep, flagsp, out,
        tc, (t0 == 0) ? 1 : 0, (t0 + tc >= T_) ? 1 : 0);
  }
}